// Round 4
// baseline (914.120 us; speedup 1.0000x reference)
//
#include <hip/hip_runtime.h>

#define D 32
#define GN 64            // receiver nodes per bin
#define CAPB_MAX 1600    // entries per bin (avg 1280, sigma ~36)
#define CHUNK_A 16384    // edges per bucket block
#define THREADS_A 512

// K0: P_src = W_aggr @ W_eu @ W_src, similarly edge, rx. One block (32,32).
__global__ void combine_weights(const float* __restrict__ W_src,
                                const float* __restrict__ W_edge,
                                const float* __restrict__ W_rx,
                                const float* __restrict__ W_eu,
                                const float* __restrict__ W_aggr,
                                float* __restrict__ P_out) {
    __shared__ float sWa[D][D], sWe[D][D], sP2[D][D + 1];
    __shared__ float sW1[D][D], sW2[D][D], sW3[D][D];
    const int j = threadIdx.x, i = threadIdx.y;
    sWa[i][j] = W_aggr[i * D + j];
    sWe[i][j] = W_eu[i * D + j];
    sW1[i][j] = W_src[i * D + j];
    sW2[i][j] = W_edge[i * D + j];
    sW3[i][j] = W_rx[i * D + j];
    __syncthreads();
    float s = 0.f;
    #pragma unroll
    for (int k = 0; k < D; ++k) s += sWa[i][k] * sWe[k][j];
    sP2[i][j] = s;
    __syncthreads();
    float a = 0.f, b = 0.f, c = 0.f;
    #pragma unroll
    for (int k = 0; k < D; ++k) {
        const float p = sP2[i][k];
        a += p * sW1[k][j];
        b += p * sW2[k][j];
        c += p * sW3[k][j];
    }
    P_out[0 * D * D + i * D + j] = a;
    P_out[1 * D * D + i * D + j] = b;
    P_out[2 * D * D + i * D + j] = c;
}

// K1: bucket edges by receiver bin (v>>6). Per (block,bin) ONE cursor atomic
// reserves a contiguous run -> line-dense writes (avg ~10 entries = 84B/run
// vs 8B scattered in R3). Entry packs (e, u<<6|v&63) in 8B.
__global__ void __launch_bounds__(THREADS_A) bucket(
    const int* __restrict__ ei,
    const float* __restrict__ x,
    const float* __restrict__ ea,
    int* __restrict__ cursor,        // [NBINS] zeroed
    uint2* __restrict__ binbuf,      // [NBINS, CAPB]
    float* __restrict__ A,           // fallback target (zeroed)
    float* __restrict__ B,
    int* __restrict__ cnt,           // fallback deg target (zeroed)
    int E_, int NBINS, int CAPB) {
    extern __shared__ int sm[];
    int* hist = sm;          // [NBINS]
    int* cur  = sm + NBINS;  // [NBINS]
    const int tid = threadIdx.x;
    for (int b = tid; b < NBINS; b += THREADS_A) hist[b] = 0;
    __syncthreads();

    const int base = blockIdx.x * CHUNK_A;
    const int end  = min(base + CHUNK_A, E_);

    // pass 1: local histogram of bins
    for (int e = base + tid; e < end; e += THREADS_A)
        atomicAdd(&hist[ei[E_ + e] >> 6], 1);
    __syncthreads();

    // reserve one contiguous global run per touched bin
    for (int b = tid; b < NBINS; b += THREADS_A) {
        const int h = hist[b];
        cur[b] = h ? atomicAdd(&cursor[b], h) : 0;
    }
    __syncthreads();

    // pass 2: append into reserved runs
    for (int e = base + tid; e < end; e += THREADS_A) {
        const int u = ei[e];
        const int v = ei[E_ + e];
        const int b = v >> 6;
        const int slot = atomicAdd(&cur[b], 1);
        if (slot < CAPB) {
            binbuf[(size_t)b * CAPB + slot] =
                make_uint2((unsigned)e, ((unsigned)u << 6) | (unsigned)(v & 63));
        } else {
            // guaranteed-correct fallback (p ~ 1e-18 at CAPB=1600)
            const float* xr = x + (size_t)u * D;
            const float* er = ea + (size_t)e * D;
            float* Ar = A + (size_t)v * D;
            float* Br = B + (size_t)v * D;
            for (int k = 0; k < D; ++k) {
                atomicAdd(Ar + k, xr[k]);
                atomicAdd(Br + k, er[k]);
            }
            atomicAdd(&cnt[v], 1);
        }
    }
}

// K2: one block per bin. Gather x[u]/ea[e] rows, accumulate into LDS via
// ds_add_f32. Row stride 33 spreads (vl + 4q + j) across banks (stride 32
// would put all groups' lane q on the same 4 banks -> 8-way conflict).
__global__ void __launch_bounds__(256) bin_gather(
    const float* __restrict__ x,
    const float* __restrict__ ea,
    const uint2* __restrict__ binbuf,
    const int* __restrict__ cursor,
    float* __restrict__ A,
    float* __restrict__ B,
    int* __restrict__ cnt,
    int N_, int CAPB) {
    __shared__ float accA[GN][D + 1];
    __shared__ float accB[GN][D + 1];
    __shared__ int cl[GN];
    const int tid = threadIdx.x;
    const int b = blockIdx.x;

    for (int i = tid; i < GN * (D + 1); i += 256) {
        ((float*)accA)[i] = 0.f;
        ((float*)accB)[i] = 0.f;
    }
    for (int r = tid; r < GN; r += 256) cl[r] = 0;
    __syncthreads();

    const int total = cursor[b];
    const int c = min(total, CAPB);
    const uint2* __restrict__ lst = binbuf + (size_t)b * CAPB;
    const int g = tid >> 3;   // 32 entry-groups
    const int q = tid & 7;    // float4 slice owner

    for (int i = g; i < c; i += 32) {
        const uint2 en = lst[i];
        const int e  = (int)en.x;
        const int u  = (int)(en.y >> 6);
        const int vl = (int)(en.y & 63);
        const float4 xv = *(const float4*)(x + (size_t)u * D + q * 4);
        const float4 ev = *(const float4*)(ea + (size_t)e * D + q * 4);
        atomicAdd(&accA[vl][q * 4 + 0], xv.x);
        atomicAdd(&accA[vl][q * 4 + 1], xv.y);
        atomicAdd(&accA[vl][q * 4 + 2], xv.z);
        atomicAdd(&accA[vl][q * 4 + 3], xv.w);
        atomicAdd(&accB[vl][q * 4 + 0], ev.x);
        atomicAdd(&accB[vl][q * 4 + 1], ev.y);
        atomicAdd(&accB[vl][q * 4 + 2], ev.z);
        atomicAdd(&accB[vl][q * 4 + 3], ev.w);
        if (q == 0) atomicAdd(&cl[vl], 1);
    }
    __syncthreads();

    // flush: merge with fallback contributions already in A/B (usually zero)
    for (int idx = tid; idx < GN * (D / 4); idx += 256) {
        const int r  = idx >> 3;        // node within bin
        const int k4 = (idx & 7) * 4;   // float4 column
        const int n = b * GN + r;
        if (n >= N_) continue;
        float* Ar = A + (size_t)n * D + k4;
        float* Br = B + (size_t)n * D + k4;
        const float4 a0 = *(const float4*)Ar;
        const float4 b0 = *(const float4*)Br;
        float4 av = { accA[r][k4 + 0] + a0.x, accA[r][k4 + 1] + a0.y,
                      accA[r][k4 + 2] + a0.z, accA[r][k4 + 3] + a0.w };
        float4 bv = { accB[r][k4 + 0] + b0.x, accB[r][k4 + 1] + b0.y,
                      accB[r][k4 + 2] + b0.z, accB[r][k4 + 3] + b0.w };
        *(float4*)Ar = av;
        *(float4*)Br = bv;
    }
    for (int r = tid; r < GN; r += 256) {
        const int n = b * GN + r;
        if (n < N_) cnt[n] += cl[r];  // cnt pre-zeroed; fallback added atomically before
    }
}

// K3: per-node epilogue. Thread = node; weight loads are wave-uniform.
__global__ void __launch_bounds__(256) node_kernel(
    const float* __restrict__ x,
    const float* __restrict__ A,
    const float* __restrict__ B,
    const int* __restrict__ cnt,
    const float* __restrict__ W_rxnode,
    const float* __restrict__ P,
    float* __restrict__ out0,
    float* __restrict__ out1,
    int N_) {
    const int n = blockIdx.x * 256 + threadIdx.x;
    if (n >= N_) return;

    float xr[D];
    #pragma unroll
    for (int kq = 0; kq < D / 4; ++kq)
        *(float4*)(xr + kq * 4) = *(const float4*)(x + (size_t)n * D + kq * 4);

    {
        float o[D];
        #pragma unroll
        for (int j = 0; j < D; ++j) {
            float s = 0.f;
            #pragma unroll
            for (int k = 0; k < D; ++k) s += xr[k] * W_rxnode[j * D + k];
            o[j] = s;
        }
        #pragma unroll
        for (int kq = 0; kq < D / 4; ++kq)
            *(float4*)(out0 + (size_t)n * D + kq * 4) = *(const float4*)(o + kq * 4);
    }

    float Ar[D], Br[D];
    #pragma unroll
    for (int kq = 0; kq < D / 4; ++kq) {
        *(float4*)(Ar + kq * 4) = *(const float4*)(A + (size_t)n * D + kq * 4);
        *(float4*)(Br + kq * 4) = *(const float4*)(B + (size_t)n * D + kq * 4);
    }
    const float dg = (float)cnt[n];
    #pragma unroll
    for (int k = 0; k < D; ++k) xr[k] *= dg;  // fold deg into x row

    const float* __restrict__ Ps = P;
    const float* __restrict__ Pe = P + D * D;
    const float* __restrict__ Pr = P + 2 * D * D;
    {
        float o[D];
        #pragma unroll
        for (int j = 0; j < D; ++j) {
            float s = 0.f;
            #pragma unroll
            for (int k = 0; k < D; ++k) {
                s += Ar[k] * Ps[j * D + k];
                s += Br[k] * Pe[j * D + k];
                s += xr[k] * Pr[j * D + k];
            }
            o[j] = s;
        }
        #pragma unroll
        for (int kq = 0; kq < D / 4; ++kq)
            *(float4*)(out1 + (size_t)n * D + kq * 4) = *(const float4*)(o + kq * 4);
    }
}

extern "C" void kernel_launch(void* const* d_in, const int* in_sizes, int n_in,
                              void* d_out, int out_size, void* d_ws, size_t ws_size,
                              hipStream_t stream) {
    const float* x        = (const float*)d_in[0];
    const int*   ei       = (const int*)d_in[1];    // [2, E] int32
    const float* ea       = (const float*)d_in[2];  // [E, D]
    const float* W_src    = (const float*)d_in[3];
    const float* W_edge   = (const float*)d_in[4];
    const float* W_rx     = (const float*)d_in[5];
    const float* W_eu     = (const float*)d_in[6];
    const float* W_rxnode = (const float*)d_in[7];
    const float* W_aggr   = (const float*)d_in[8];

    const int N_ = in_sizes[0] / D;  // 100000
    const int E_ = in_sizes[2] / D;  // 2000000
    const int NBINS = (N_ + GN - 1) / GN;

    // ws layout: A[N*D] | B[N*D] | cnt[N] | cursor[NBINS]  (zeroed region)
    //            | P[3*D*D] | pad | binbuf[NBINS*CAPB] uint2
    float* A      = (float*)d_ws;
    float* B      = A + (size_t)N_ * D;
    int*   cnt    = (int*)(B + (size_t)N_ * D);
    int*   cursor = cnt + N_;
    float* P      = (float*)(cursor + NBINS);
    size_t off = ((size_t)2 * N_ * D + N_ + NBINS + 3 * D * D) * 4;
    off = (off + 15) & ~(size_t)15;
    uint2* binbuf = (uint2*)((char*)d_ws + off);

    int CAPB = 0;
    if (ws_size > off) {
        size_t c = (ws_size - off) / ((size_t)NBINS * 8);
        CAPB = (c > CAPB_MAX) ? CAPB_MAX : (int)c;
    }

    float* out0 = (float*)d_out;
    float* out1 = out0 + (size_t)N_ * D;

    // zero A, B, cnt, cursor (contiguous)
    hipMemsetAsync(d_ws, 0, ((size_t)2 * N_ * D + N_ + NBINS) * sizeof(float), stream);

    combine_weights<<<1, dim3(32, 32), 0, stream>>>(W_src, W_edge, W_rx, W_eu, W_aggr, P);

    const int gridA = (E_ + CHUNK_A - 1) / CHUNK_A;
    bucket<<<gridA, THREADS_A, (size_t)NBINS * 2 * sizeof(int), stream>>>(
        ei, x, ea, cursor, binbuf, A, B, cnt, E_, NBINS, CAPB);

    bin_gather<<<NBINS, 256, 0, stream>>>(x, ea, binbuf, cursor, A, B, cnt, N_, CAPB);

    node_kernel<<<(N_ + 255) / 256, 256, 0, stream>>>(x, A, B, cnt, W_rxnode, P, out0, out1, N_);
}

// Round 5
// 897.265 us; speedup vs baseline: 1.0188x; 1.0188x over previous
//
#include <hip/hip_runtime.h>

#define D 32
#define GN 64            // receiver nodes per bin
#define CAPB_MAX 1600    // entries per bin (avg 1280, +8.9 sigma)
#define CHUNK_A 8192     // edges per bucket block
#define THREADS_A 512
#define THREADS_G 512

// K0: P_src = W_aggr @ W_eu @ W_src, similarly edge, rx. One block (32,32).
__global__ void combine_weights(const float* __restrict__ W_src,
                                const float* __restrict__ W_edge,
                                const float* __restrict__ W_rx,
                                const float* __restrict__ W_eu,
                                const float* __restrict__ W_aggr,
                                float* __restrict__ P_out) {
    __shared__ float sWa[D][D], sWe[D][D], sP2[D][D + 1];
    __shared__ float sW1[D][D], sW2[D][D], sW3[D][D];
    const int j = threadIdx.x, i = threadIdx.y;
    sWa[i][j] = W_aggr[i * D + j];
    sWe[i][j] = W_eu[i * D + j];
    sW1[i][j] = W_src[i * D + j];
    sW2[i][j] = W_edge[i * D + j];
    sW3[i][j] = W_rx[i * D + j];
    __syncthreads();
    float s = 0.f;
    #pragma unroll
    for (int k = 0; k < D; ++k) s += sWa[i][k] * sWe[k][j];
    sP2[i][j] = s;
    __syncthreads();
    float a = 0.f, b = 0.f, c = 0.f;
    #pragma unroll
    for (int k = 0; k < D; ++k) {
        const float p = sP2[i][k];
        a += p * sW1[k][j];
        b += p * sW2[k][j];
        c += p * sW3[k][j];
    }
    P_out[0 * D * D + i * D + j] = a;
    P_out[1 * D * D + i * D + j] = b;
    P_out[2 * D * D + i * D + j] = c;
}

// K1: bucket edges by receiver bin (v>>6). Per (block,bin) ONE cursor atomic
// reserves a contiguous run -> line-dense writes. Entry packs (e, u<<6|v&63).
__global__ void __launch_bounds__(THREADS_A) bucket(
    const int* __restrict__ ei,
    const float* __restrict__ x,
    const float* __restrict__ ea,
    int* __restrict__ cursor,        // [NBINS] zeroed
    uint2* __restrict__ binbuf,      // [NBINS, CAPB]
    float* __restrict__ A,           // fallback target (zeroed)
    float* __restrict__ B,
    int* __restrict__ cnt,           // fallback deg target (zeroed)
    int E_, int NBINS, int CAPB) {
    extern __shared__ int sm[];
    int* hist = sm;          // [NBINS]
    int* cur  = sm + NBINS;  // [NBINS]
    const int tid = threadIdx.x;
    for (int b = tid; b < NBINS; b += THREADS_A) hist[b] = 0;
    __syncthreads();

    const int base = blockIdx.x * CHUNK_A;
    const int end  = min(base + CHUNK_A, E_);

    for (int e = base + tid; e < end; e += THREADS_A)
        atomicAdd(&hist[ei[E_ + e] >> 6], 1);
    __syncthreads();

    for (int b = tid; b < NBINS; b += THREADS_A) {
        const int h = hist[b];
        cur[b] = h ? atomicAdd(&cursor[b], h) : 0;
    }
    __syncthreads();

    for (int e = base + tid; e < end; e += THREADS_A) {
        const int u = ei[e];
        const int v = ei[E_ + e];
        const int b = v >> 6;
        const int slot = atomicAdd(&cur[b], 1);
        if (slot < CAPB) {
            binbuf[(size_t)b * CAPB + slot] =
                make_uint2((unsigned)e, ((unsigned)u << 6) | (unsigned)(v & 63));
        } else {
            // guaranteed-correct fallback (p ~ 1e-16 at CAPB=1600)
            const float* xr = x + (size_t)u * D;
            const float* er = ea + (size_t)e * D;
            float* Ar = A + (size_t)v * D;
            float* Br = B + (size_t)v * D;
            for (int k = 0; k < D; ++k) {
                atomicAdd(Ar + k, xr[k]);
                atomicAdd(Br + k, er[k]);
            }
            atomicAdd(&cnt[v], 1);
        }
    }
}

// K2: one block (512 thr) per bin. Depth-2 software pipeline:
//   entries fetched 2 steps ahead, x/ea rows issued 1 step ahead,
//   ds_add consumes rows loaded one iteration earlier (R2's trick, deeper).
// LDS acc row stride 33 avoids systematic bank conflicts.
__global__ void __launch_bounds__(THREADS_G) bin_gather(
    const float* __restrict__ x,
    const float* __restrict__ ea,
    const uint2* __restrict__ binbuf,
    const int* __restrict__ cursor,
    float* __restrict__ A,
    float* __restrict__ B,
    int* __restrict__ cnt,
    int N_, int CAPB) {
    __shared__ float accA[GN][D + 1];
    __shared__ float accB[GN][D + 1];
    __shared__ int cl[GN];
    const int tid = threadIdx.x;
    const int b = blockIdx.x;

    for (int i = tid; i < GN * (D + 1); i += THREADS_G) {
        ((float*)accA)[i] = 0.f;
        ((float*)accB)[i] = 0.f;
    }
    for (int r = tid; r < GN; r += THREADS_G) cl[r] = 0;
    __syncthreads();

    const int c = min(cursor[b], CAPB);
    const uint2* __restrict__ lst = binbuf + (size_t)b * CAPB;
    const int g = tid >> 3;            // 64 entry-groups
    const int q = tid & 7;             // float4 slice owner
    const int STEP = THREADS_G / 8;    // 64

    uint2 enA = make_uint2(0u, 0u), enB = make_uint2(0u, 0u);
    float4 xvA = {0.f, 0.f, 0.f, 0.f}, evA = {0.f, 0.f, 0.f, 0.f};

    if (g < c) {
        enA = lst[g];
        if (g + STEP < c) enB = lst[g + STEP];
        xvA = *(const float4*)(x + (size_t)(enA.y >> 6) * D + q * 4);
        evA = *(const float4*)(ea + (size_t)enA.x * D + q * 4);
    }

    for (int i = g; i < c; i += STEP) {
        // stage 2-ahead entry fetch
        uint2 enC = enB;
        if (i + 2 * STEP < c) enC = lst[i + 2 * STEP];
        // stage 1-ahead row fetch
        float4 xvB = {0.f, 0.f, 0.f, 0.f}, evB = {0.f, 0.f, 0.f, 0.f};
        if (i + STEP < c) {
            xvB = *(const float4*)(x + (size_t)(enB.y >> 6) * D + q * 4);
            evB = *(const float4*)(ea + (size_t)enB.x * D + q * 4);
        }
        // consume current (rows issued one iteration ago)
        const int vl = (int)(enA.y & 63u);
        atomicAdd(&accA[vl][q * 4 + 0], xvA.x);
        atomicAdd(&accA[vl][q * 4 + 1], xvA.y);
        atomicAdd(&accA[vl][q * 4 + 2], xvA.z);
        atomicAdd(&accA[vl][q * 4 + 3], xvA.w);
        atomicAdd(&accB[vl][q * 4 + 0], evA.x);
        atomicAdd(&accB[vl][q * 4 + 1], evA.y);
        atomicAdd(&accB[vl][q * 4 + 2], evA.z);
        atomicAdd(&accB[vl][q * 4 + 3], evA.w);
        if (q == 0) atomicAdd(&cl[vl], 1);

        enA = enB; enB = enC; xvA = xvB; evA = evB;
    }
    __syncthreads();

    // flush: merge with fallback contributions already in A/B (usually zero)
    for (int idx = tid; idx < GN * (D / 4); idx += THREADS_G) {
        const int r  = idx >> 3;
        const int k4 = (idx & 7) * 4;
        const int n = b * GN + r;
        if (n >= N_) continue;
        float* Ar = A + (size_t)n * D + k4;
        float* Br = B + (size_t)n * D + k4;
        const float4 a0 = *(const float4*)Ar;
        const float4 b0 = *(const float4*)Br;
        float4 av = { accA[r][k4 + 0] + a0.x, accA[r][k4 + 1] + a0.y,
                      accA[r][k4 + 2] + a0.z, accA[r][k4 + 3] + a0.w };
        float4 bv = { accB[r][k4 + 0] + b0.x, accB[r][k4 + 1] + b0.y,
                      accB[r][k4 + 2] + b0.z, accB[r][k4 + 3] + b0.w };
        *(float4*)Ar = av;
        *(float4*)Br = bv;
    }
    for (int r = tid; r < GN; r += THREADS_G) {
        const int n = b * GN + r;
        if (n < N_) cnt[n] += cl[r];
    }
}

// K3: per-node epilogue. Thread = node; weight loads are wave-uniform.
__global__ void __launch_bounds__(256) node_kernel(
    const float* __restrict__ x,
    const float* __restrict__ A,
    const float* __restrict__ B,
    const int* __restrict__ cnt,
    const float* __restrict__ W_rxnode,
    const float* __restrict__ P,
    float* __restrict__ out0,
    float* __restrict__ out1,
    int N_) {
    const int n = blockIdx.x * 256 + threadIdx.x;
    if (n >= N_) return;

    float xr[D];
    #pragma unroll
    for (int kq = 0; kq < D / 4; ++kq)
        *(float4*)(xr + kq * 4) = *(const float4*)(x + (size_t)n * D + kq * 4);

    {
        float o[D];
        #pragma unroll
        for (int j = 0; j < D; ++j) {
            float s = 0.f;
            #pragma unroll
            for (int k = 0; k < D; ++k) s += xr[k] * W_rxnode[j * D + k];
            o[j] = s;
        }
        #pragma unroll
        for (int kq = 0; kq < D / 4; ++kq)
            *(float4*)(out0 + (size_t)n * D + kq * 4) = *(const float4*)(o + kq * 4);
    }

    float Ar[D], Br[D];
    #pragma unroll
    for (int kq = 0; kq < D / 4; ++kq) {
        *(float4*)(Ar + kq * 4) = *(const float4*)(A + (size_t)n * D + kq * 4);
        *(float4*)(Br + kq * 4) = *(const float4*)(B + (size_t)n * D + kq * 4);
    }
    const float dg = (float)cnt[n];
    #pragma unroll
    for (int k = 0; k < D; ++k) xr[k] *= dg;

    const float* __restrict__ Ps = P;
    const float* __restrict__ Pe = P + D * D;
    const float* __restrict__ Pr = P + 2 * D * D;
    {
        float o[D];
        #pragma unroll
        for (int j = 0; j < D; ++j) {
            float s = 0.f;
            #pragma unroll
            for (int k = 0; k < D; ++k) {
                s += Ar[k] * Ps[j * D + k];
                s += Br[k] * Pe[j * D + k];
                s += xr[k] * Pr[j * D + k];
            }
            o[j] = s;
        }
        #pragma unroll
        for (int kq = 0; kq < D / 4; ++kq)
            *(float4*)(out1 + (size_t)n * D + kq * 4) = *(const float4*)(o + kq * 4);
    }
}

extern "C" void kernel_launch(void* const* d_in, const int* in_sizes, int n_in,
                              void* d_out, int out_size, void* d_ws, size_t ws_size,
                              hipStream_t stream) {
    const float* x        = (const float*)d_in[0];
    const int*   ei       = (const int*)d_in[1];    // [2, E] int32
    const float* ea       = (const float*)d_in[2];  // [E, D]
    const float* W_src    = (const float*)d_in[3];
    const float* W_edge   = (const float*)d_in[4];
    const float* W_rx     = (const float*)d_in[5];
    const float* W_eu     = (const float*)d_in[6];
    const float* W_rxnode = (const float*)d_in[7];
    const float* W_aggr   = (const float*)d_in[8];

    const int N_ = in_sizes[0] / D;  // 100000
    const int E_ = in_sizes[2] / D;  // 2000000
    const int NBINS = (N_ + GN - 1) / GN;

    // ws layout: A[N*D] | B[N*D] | cnt[N] | cursor[NBINS]  (zeroed region)
    //            | P[3*D*D] | pad | binbuf[NBINS*CAPB] uint2
    float* A      = (float*)d_ws;
    float* B      = A + (size_t)N_ * D;
    int*   cnt    = (int*)(B + (size_t)N_ * D);
    int*   cursor = cnt + N_;
    float* P      = (float*)(cursor + NBINS);
    size_t off = ((size_t)2 * N_ * D + N_ + NBINS + 3 * D * D) * 4;
    off = (off + 15) & ~(size_t)15;
    uint2* binbuf = (uint2*)((char*)d_ws + off);

    int CAPB = 0;
    if (ws_size > off) {
        size_t c = (ws_size - off) / ((size_t)NBINS * 8);
        CAPB = (c > CAPB_MAX) ? CAPB_MAX : (int)c;
    }

    float* out0 = (float*)d_out;
    float* out1 = out0 + (size_t)N_ * D;

    hipMemsetAsync(d_ws, 0, ((size_t)2 * N_ * D + N_ + NBINS) * sizeof(float), stream);

    combine_weights<<<1, dim3(32, 32), 0, stream>>>(W_src, W_edge, W_rx, W_eu, W_aggr, P);

    const int gridA = (E_ + CHUNK_A - 1) / CHUNK_A;
    bucket<<<gridA, THREADS_A, (size_t)NBINS * 2 * sizeof(int), stream>>>(
        ei, x, ea, cursor, binbuf, A, B, cnt, E_, NBINS, CAPB);

    bin_gather<<<NBINS, THREADS_G, 0, stream>>>(x, ea, binbuf, cursor, A, B, cnt, N_, CAPB);

    node_kernel<<<(N_ + 255) / 256, 256, 0, stream>>>(x, A, B, cnt, W_rxnode, P, out0, out1, N_);
}

// Round 6
// 517.400 us; speedup vs baseline: 1.7668x; 1.7342x over previous
//
#include <hip/hip_runtime.h>

#define D 32
#define GN 64            // receiver nodes per bin
#define CAPB_MAX 1600    // entries per bin (avg 1280, +8.9 sigma)
#define CHUNK_A 8192     // edges per bucket block
#define THREADS_A 512
#define THREADS_G 512

// K0: P_src = W_aggr @ W_eu @ W_src, similarly edge, rx. One block (32,32).
__global__ void combine_weights(const float* __restrict__ W_src,
                                const float* __restrict__ W_edge,
                                const float* __restrict__ W_rx,
                                const float* __restrict__ W_eu,
                                const float* __restrict__ W_aggr,
                                float* __restrict__ P_out) {
    __shared__ float sWa[D][D], sWe[D][D], sP2[D][D + 1];
    __shared__ float sW1[D][D], sW2[D][D], sW3[D][D];
    const int j = threadIdx.x, i = threadIdx.y;
    sWa[i][j] = W_aggr[i * D + j];
    sWe[i][j] = W_eu[i * D + j];
    sW1[i][j] = W_src[i * D + j];
    sW2[i][j] = W_edge[i * D + j];
    sW3[i][j] = W_rx[i * D + j];
    __syncthreads();
    float s = 0.f;
    #pragma unroll
    for (int k = 0; k < D; ++k) s += sWa[i][k] * sWe[k][j];
    sP2[i][j] = s;
    __syncthreads();
    float a = 0.f, b = 0.f, c = 0.f;
    #pragma unroll
    for (int k = 0; k < D; ++k) {
        const float p = sP2[i][k];
        a += p * sW1[k][j];
        b += p * sW2[k][j];
        c += p * sW3[k][j];
    }
    P_out[0 * D * D + i * D + j] = a;
    P_out[1 * D * D + i * D + j] = b;
    P_out[2 * D * D + i * D + j] = c;
}

// K1: bucket edges by receiver bin (v>>6). Per (block,bin) ONE cursor atomic
// reserves a contiguous run -> line-dense writes. v cached in LDS so ei's
// v-half is read once. Entry packs (e, u<<6|v&63).
__global__ void __launch_bounds__(THREADS_A) bucket(
    const int* __restrict__ ei,
    const float* __restrict__ x,
    const float* __restrict__ ea,
    int* __restrict__ cursor,        // [NBINS] zeroed
    uint2* __restrict__ binbuf,      // [NBINS, CAPB]
    float* __restrict__ A,           // fallback target (zeroed)
    float* __restrict__ B,
    int* __restrict__ cnt,           // fallback deg target (zeroed)
    int E_, int NBINS, int CAPB) {
    extern __shared__ int sm[];
    int* hist = sm;              // [NBINS]
    int* cur  = sm + NBINS;      // [NBINS]
    int* sv   = sm + 2 * NBINS;  // [CHUNK_A]
    const int tid = threadIdx.x;
    for (int b = tid; b < NBINS; b += THREADS_A) hist[b] = 0;
    __syncthreads();

    const int base = blockIdx.x * CHUNK_A;
    const int m = min(CHUNK_A, E_ - base);

    for (int idx = tid; idx < m; idx += THREADS_A) {
        const int v = ei[E_ + base + idx];
        sv[idx] = v;
        atomicAdd(&hist[v >> 6], 1);
    }
    __syncthreads();

    for (int b = tid; b < NBINS; b += THREADS_A) {
        const int h = hist[b];
        cur[b] = h ? atomicAdd(&cursor[b], h) : 0;
    }
    __syncthreads();

    for (int idx = tid; idx < m; idx += THREADS_A) {
        const int u = ei[base + idx];
        const int v = sv[idx];
        const int bb = v >> 6;
        const int slot = atomicAdd(&cur[bb], 1);
        if (slot < CAPB) {
            binbuf[(size_t)bb * CAPB + slot] =
                make_uint2((unsigned)(base + idx),
                           ((unsigned)u << 6) | (unsigned)(v & 63));
        } else {
            // guaranteed-correct fallback (p ~ 1e-16 at CAPB=1600)
            const int e = base + idx;
            const float* xr = x + (size_t)u * D;
            const float* er = ea + (size_t)e * D;
            float* Ar = A + (size_t)v * D;
            float* Br = B + (size_t)v * D;
            for (int k = 0; k < D; ++k) {
                atomicAdd(Ar + k, xr[k]);
                atomicAdd(Br + k, er[k]);
            }
            atomicAdd(&cnt[v], 1);
        }
    }
}

// K2 (fused): counting-sort bin entries by node in LDS (2 LDS atomics/edge,
// not 64), then per-node REGISTER accumulation (no LDS atomics on hot path),
// then epilogue (out0, out1) in-block. node_kernel eliminated.
__global__ void __launch_bounds__(THREADS_G) bin_gather(
    const float* __restrict__ x,
    const float* __restrict__ ea,
    const uint2* __restrict__ binbuf,
    const int* __restrict__ cursor,
    const float* __restrict__ Afb,   // fallback accum (read-only here)
    const float* __restrict__ Bfb,
    const int* __restrict__ cntfb,
    const float* __restrict__ W_rxnode,
    const float* __restrict__ P,     // Ps, Pe, Pr
    float* __restrict__ out0,
    float* __restrict__ out1,
    int N_, int CAPB) {
    // uni: first holds raw entries ent[], later reused as sA/sB accumulators
    __shared__ __align__(16) char uni[2 * GN * (D + 1) * 4];  // 16896 B >= CAPB_MAX*8? no: ent capacity 2112 entries
    uint2* ent = (uint2*)uni;
    float (*sA)[D + 1] = (float (*)[D + 1])uni;
    float (*sB)[D + 1] = ((float (*)[D + 1])uni) + GN;
    __shared__ uint2 ordb[CAPB_MAX];
    __shared__ int cl[GN], cl2[GN], st[GN];

    const int tid = threadIdx.x;
    const int b = blockIdx.x;

    if (tid < GN) { cl[tid] = 0; cl2[tid] = 0; }
    __syncthreads();

    const int c = min(cursor[b], CAPB);
    const uint2* __restrict__ lst = binbuf + (size_t)b * CAPB;

    // load entries + per-node histogram (1 LDS atomic per entry)
    for (int i = tid; i < c; i += THREADS_G) {
        const uint2 en = lst[i];
        ent[i] = en;
        atomicAdd(&cl[en.y & 63u], 1);
    }
    __syncthreads();

    // exclusive prefix sum of cl -> st (Hillis-Steele over 64)
    if (tid < GN) st[tid] = cl[tid];
    __syncthreads();
    for (int off = 1; off < GN; off <<= 1) {
        int v = 0;
        if (tid < GN && tid >= off) v = st[tid - off];
        __syncthreads();
        if (tid < GN && tid >= off) st[tid] += v;
        __syncthreads();
    }
    if (tid < GN) st[tid] -= cl[tid];
    __syncthreads();

    // counting-sort scatter into ordb (1 LDS atomic per entry)
    for (int i = tid; i < c; i += THREADS_G) {
        const uint2 en = ent[i];
        const int vl = (int)(en.y & 63u);
        const int slot = atomicAdd(&cl2[vl], 1);
        ordb[st[vl] + slot] = en;
    }
    __syncthreads();  // ent dead from here; uni becomes sA/sB

    // per-node register gather: group g (8 lanes) owns node b*GN+g
    const int g = tid >> 3;
    const int q = tid & 7;
    const int s = st[g];
    const int len = cl[g];
    const int n = b * GN + g;

    float4 aA = {0.f, 0.f, 0.f, 0.f}, aB = {0.f, 0.f, 0.f, 0.f};
    uint2 e0 = make_uint2(0u, 0u);
    float4 xv = {0.f, 0.f, 0.f, 0.f}, ev = {0.f, 0.f, 0.f, 0.f};
    if (len > 0) {
        e0 = ordb[s];
        xv = *(const float4*)(x + (size_t)(e0.y >> 6) * D + q * 4);
        ev = *(const float4*)(ea + (size_t)e0.x * D + q * 4);
    }
    for (int i = 0; i < len; ++i) {
        uint2 e1 = e0;
        float4 xv1 = xv, ev1 = ev;
        if (i + 1 < len) {
            e1 = ordb[s + i + 1];
            xv1 = *(const float4*)(x + (size_t)(e1.y >> 6) * D + q * 4);
            ev1 = *(const float4*)(ea + (size_t)e1.x * D + q * 4);
        }
        aA.x += xv.x; aA.y += xv.y; aA.z += xv.z; aA.w += xv.w;
        aB.x += ev.x; aB.y += ev.y; aB.z += ev.z; aB.w += ev.w;
        e0 = e1; xv = xv1; ev = ev1;
    }

    // merge rare fallback contributions, park accumulators in LDS
    if (n < N_) {
        const float4 fa = *(const float4*)(Afb + (size_t)n * D + q * 4);
        const float4 fb = *(const float4*)(Bfb + (size_t)n * D + q * 4);
        sA[g][q * 4 + 0] = aA.x + fa.x;
        sA[g][q * 4 + 1] = aA.y + fa.y;
        sA[g][q * 4 + 2] = aA.z + fa.z;
        sA[g][q * 4 + 3] = aA.w + fa.w;
        sB[g][q * 4 + 0] = aB.x + fb.x;
        sB[g][q * 4 + 1] = aB.y + fb.y;
        sB[g][q * 4 + 2] = aB.z + fb.z;
        sB[g][q * 4 + 3] = aB.w + fb.w;
    }
    __syncthreads();

    // fused epilogue: thread (g,q) computes outputs j = 4q..4q+3 of node n
    if (n < N_) {
        float xr[D];
        #pragma unroll
        for (int kq = 0; kq < D / 4; ++kq)
            *(float4*)(xr + kq * 4) = *(const float4*)(x + (size_t)n * D + kq * 4);
        const float dg = (float)(len + cntfb[n]);
        const float* __restrict__ Ps = P;
        const float* __restrict__ Pe = P + D * D;
        const float* __restrict__ Pr = P + 2 * D * D;
        float o0[4], o1[4];
        #pragma unroll
        for (int jj = 0; jj < 4; ++jj) {
            const int j = q * 4 + jj;
            float s0 = 0.f, s1 = 0.f, s1r = 0.f;
            #pragma unroll
            for (int k = 0; k < D; ++k) {
                s0  += xr[k] * W_rxnode[j * D + k];
                s1  += sA[g][k] * Ps[j * D + k] + sB[g][k] * Pe[j * D + k];
                s1r += xr[k] * Pr[j * D + k];
            }
            o0[jj] = s0;
            o1[jj] = s1 + dg * s1r;
        }
        *(float4*)(out0 + (size_t)n * D + q * 4) = *(const float4*)o0;
        *(float4*)(out1 + (size_t)n * D + q * 4) = *(const float4*)o1;
    }
}

extern "C" void kernel_launch(void* const* d_in, const int* in_sizes, int n_in,
                              void* d_out, int out_size, void* d_ws, size_t ws_size,
                              hipStream_t stream) {
    const float* x        = (const float*)d_in[0];
    const int*   ei       = (const int*)d_in[1];    // [2, E] int32
    const float* ea       = (const float*)d_in[2];  // [E, D]
    const float* W_src    = (const float*)d_in[3];
    const float* W_edge   = (const float*)d_in[4];
    const float* W_rx     = (const float*)d_in[5];
    const float* W_eu     = (const float*)d_in[6];
    const float* W_rxnode = (const float*)d_in[7];
    const float* W_aggr   = (const float*)d_in[8];

    const int N_ = in_sizes[0] / D;  // 100000
    const int E_ = in_sizes[2] / D;  // 2000000
    const int NBINS = (N_ + GN - 1) / GN;

    // ws layout: A[N*D] | B[N*D] | cnt[N] | cursor[NBINS]  (zeroed region)
    //            | P[3*D*D] | pad | binbuf[NBINS*CAPB] uint2
    float* A      = (float*)d_ws;
    float* B      = A + (size_t)N_ * D;
    int*   cnt    = (int*)(B + (size_t)N_ * D);
    int*   cursor = cnt + N_;
    float* P      = (float*)(cursor + NBINS);
    size_t off = ((size_t)2 * N_ * D + N_ + NBINS + 3 * D * D) * 4;
    off = (off + 15) & ~(size_t)15;
    uint2* binbuf = (uint2*)((char*)d_ws + off);

    int CAPB = 0;
    if (ws_size > off) {
        size_t c = (ws_size - off) / ((size_t)NBINS * 8);
        CAPB = (c > CAPB_MAX) ? CAPB_MAX : (int)c;
    }

    float* out0 = (float*)d_out;
    float* out1 = out0 + (size_t)N_ * D;

    // zero A, B, cnt, cursor (contiguous)
    hipMemsetAsync(d_ws, 0, ((size_t)2 * N_ * D + N_ + NBINS) * sizeof(float), stream);

    combine_weights<<<1, dim3(32, 32), 0, stream>>>(W_src, W_edge, W_rx, W_eu, W_aggr, P);

    const int gridA = (E_ + CHUNK_A - 1) / CHUNK_A;
    const size_t smA = (size_t)(2 * NBINS + CHUNK_A) * sizeof(int);
    bucket<<<gridA, THREADS_A, smA, stream>>>(
        ei, x, ea, cursor, binbuf, A, B, cnt, E_, NBINS, CAPB);

    bin_gather<<<NBINS, THREADS_G, 0, stream>>>(
        x, ea, binbuf, cursor, A, B, cnt, W_rxnode, P, out0, out1, N_, CAPB);
}

// Round 7
// 242.394 us; speedup vs baseline: 3.7712x; 2.1345x over previous
//
#include <hip/hip_runtime.h>

#define D 32
#define GN 64            // receiver nodes per bin
#define CAPB_MAX 1600    // entries per bin (avg 1280, +8.9 sigma)
#define CHUNK_A 8192     // edges per bucket block
#define THREADS_A 512
#define THREADS_G 512

// K0: P_src = W_aggr @ W_eu @ W_src, similarly edge, rx. One block (32,32).
__global__ void combine_weights(const float* __restrict__ W_src,
                                const float* __restrict__ W_edge,
                                const float* __restrict__ W_rx,
                                const float* __restrict__ W_eu,
                                const float* __restrict__ W_aggr,
                                float* __restrict__ P_out) {
    __shared__ float sWa[D][D], sWe[D][D], sP2[D][D + 1];
    __shared__ float sW1[D][D], sW2[D][D], sW3[D][D];
    const int j = threadIdx.x, i = threadIdx.y;
    sWa[i][j] = W_aggr[i * D + j];
    sWe[i][j] = W_eu[i * D + j];
    sW1[i][j] = W_src[i * D + j];
    sW2[i][j] = W_edge[i * D + j];
    sW3[i][j] = W_rx[i * D + j];
    __syncthreads();
    float s = 0.f;
    #pragma unroll
    for (int k = 0; k < D; ++k) s += sWa[i][k] * sWe[k][j];
    sP2[i][j] = s;
    __syncthreads();
    float a = 0.f, b = 0.f, c = 0.f;
    #pragma unroll
    for (int k = 0; k < D; ++k) {
        const float p = sP2[i][k];
        a += p * sW1[k][j];
        b += p * sW2[k][j];
        c += p * sW3[k][j];
    }
    P_out[0 * D * D + i * D + j] = a;
    P_out[1 * D * D + i * D + j] = b;
    P_out[2 * D * D + i * D + j] = c;
}

// K1: bucket edges by receiver bin (v>>6). Per (block,bin) ONE cursor atomic
// reserves a contiguous run -> line-dense writes. Entry packs (e, u<<6|v&63).
__global__ void __launch_bounds__(THREADS_A) bucket(
    const int* __restrict__ ei,
    const float* __restrict__ x,
    const float* __restrict__ ea,
    int* __restrict__ cursor,        // [NBINS] zeroed
    uint2* __restrict__ binbuf,      // [NBINS, CAPB]
    float* __restrict__ A,           // fallback target (zeroed)
    float* __restrict__ B,
    int* __restrict__ cntfb,         // fallback deg target (zeroed)
    int* __restrict__ ovf,           // overflow flag (zeroed)
    int E_, int NBINS, int CAPB) {
    extern __shared__ int sm[];
    int* hist = sm;              // [NBINS]
    int* cur  = sm + NBINS;      // [NBINS]
    int* sv   = sm + 2 * NBINS;  // [CHUNK_A]
    const int tid = threadIdx.x;
    for (int b = tid; b < NBINS; b += THREADS_A) hist[b] = 0;
    __syncthreads();

    const int base = blockIdx.x * CHUNK_A;
    const int m = min(CHUNK_A, E_ - base);

    for (int idx = tid; idx < m; idx += THREADS_A) {
        const int v = ei[E_ + base + idx];
        sv[idx] = v;
        atomicAdd(&hist[v >> 6], 1);
    }
    __syncthreads();

    for (int b = tid; b < NBINS; b += THREADS_A) {
        const int h = hist[b];
        cur[b] = h ? atomicAdd(&cursor[b], h) : 0;
    }
    __syncthreads();

    for (int idx = tid; idx < m; idx += THREADS_A) {
        const int u = ei[base + idx];
        const int v = sv[idx];
        const int bb = v >> 6;
        const int slot = atomicAdd(&cur[bb], 1);
        if (slot < CAPB) {
            binbuf[(size_t)bb * CAPB + slot] =
                make_uint2((unsigned)(base + idx),
                           ((unsigned)u << 6) | (unsigned)(v & 63));
        } else {
            // guaranteed-correct fallback (p ~ 1e-16 at CAPB=1600)
            atomicOr(ovf, 1);
            const int e = base + idx;
            const float* xr = x + (size_t)u * D;
            const float* er = ea + (size_t)e * D;
            float* Ar = A + (size_t)v * D;
            float* Br = B + (size_t)v * D;
            for (int k = 0; k < D; ++k) {
                atomicAdd(Ar + k, xr[k]);
                atomicAdd(Br + k, er[k]);
            }
            atomicAdd(&cntfb[v], 1);
        }
    }
}

// K2: counting-sort bin entries by node in LDS (2 LDS atomics/edge), then
// per-node REGISTER accumulation (no LDS atomics, no spills), write A/B/deg.
// Epilogue deliberately NOT fused (R6: fusion -> 128 VGPR + 300MB spill).
__global__ void __launch_bounds__(THREADS_G) bin_gather(
    const float* __restrict__ x,
    const float* __restrict__ ea,
    const uint2* __restrict__ binbuf,
    const int* __restrict__ cursor,
    const float* __restrict__ Afb,   // fallback accum (read only if ovf)
    const float* __restrict__ Bfb,
    const int* __restrict__ cntfb,
    const int* __restrict__ ovf,
    float* __restrict__ A,           // final accum out (same buf as Afb ok)
    float* __restrict__ B,
    int* __restrict__ deg,
    int N_, int CAPB) {
    __shared__ uint2 ent[CAPB_MAX];
    __shared__ uint2 ordb[CAPB_MAX];
    __shared__ int cl[GN], cl2[GN], st[GN];

    const int tid = threadIdx.x;
    const int b = blockIdx.x;

    if (tid < GN) { cl[tid] = 0; cl2[tid] = 0; }
    __syncthreads();

    const int c = min(cursor[b], CAPB);
    const uint2* __restrict__ lst = binbuf + (size_t)b * CAPB;

    // load entries + per-node histogram (1 LDS atomic per entry)
    for (int i = tid; i < c; i += THREADS_G) {
        const uint2 en = lst[i];
        ent[i] = en;
        atomicAdd(&cl[en.y & 63u], 1);
    }
    __syncthreads();

    // exclusive prefix sum of cl -> st
    if (tid < GN) st[tid] = cl[tid];
    __syncthreads();
    for (int off = 1; off < GN; off <<= 1) {
        int v = 0;
        if (tid < GN && tid >= off) v = st[tid - off];
        __syncthreads();
        if (tid < GN && tid >= off) st[tid] += v;
        __syncthreads();
    }
    if (tid < GN) st[tid] -= cl[tid];
    __syncthreads();

    // counting-sort scatter (1 LDS atomic per entry)
    for (int i = tid; i < c; i += THREADS_G) {
        const uint2 en = ent[i];
        const int vl = (int)(en.y & 63u);
        const int slot = atomicAdd(&cl2[vl], 1);
        ordb[st[vl] + slot] = en;
    }
    __syncthreads();

    // per-node register gather: group g (8 lanes) owns node b*GN+g
    const int g = tid >> 3;
    const int q = tid & 7;
    const int s = st[g];
    const int len = cl[g];
    const int n = b * GN + g;

    float4 aA = {0.f, 0.f, 0.f, 0.f}, aB = {0.f, 0.f, 0.f, 0.f};
    uint2 e0 = make_uint2(0u, 0u);
    float4 xv = {0.f, 0.f, 0.f, 0.f}, ev = {0.f, 0.f, 0.f, 0.f};
    if (len > 0) {
        e0 = ordb[s];
        xv = *(const float4*)(x + (size_t)(e0.y >> 6) * D + q * 4);
        ev = *(const float4*)(ea + (size_t)e0.x * D + q * 4);
    }
    for (int i = 0; i < len; ++i) {
        uint2 e1 = e0;
        float4 xv1 = xv, ev1 = ev;
        if (i + 1 < len) {
            e1 = ordb[s + i + 1];
            xv1 = *(const float4*)(x + (size_t)(e1.y >> 6) * D + q * 4);
            ev1 = *(const float4*)(ea + (size_t)e1.x * D + q * 4);
        }
        aA.x += xv.x; aA.y += xv.y; aA.z += xv.z; aA.w += xv.w;
        aB.x += ev.x; aB.y += ev.y; aB.z += ev.z; aB.w += ev.w;
        e0 = e1; xv = xv1; ev = ev1;
    }

    if (n < N_) {
        int dtot = len;
        if (*ovf) {  // rare: merge fallback contributions
            const float4 fa = *(const float4*)(Afb + (size_t)n * D + q * 4);
            const float4 fb = *(const float4*)(Bfb + (size_t)n * D + q * 4);
            aA.x += fa.x; aA.y += fa.y; aA.z += fa.z; aA.w += fa.w;
            aB.x += fb.x; aB.y += fb.y; aB.z += fb.z; aB.w += fb.w;
            dtot += cntfb[n];
        }
        *(float4*)(A + (size_t)n * D + q * 4) = aA;
        *(float4*)(B + (size_t)n * D + q * 4) = aB;
        if (q == 0) deg[n] = dtot;
    }
}

// K3: per-node epilogue. Thread = node; weight loads are wave-uniform.
__global__ void __launch_bounds__(256) node_kernel(
    const float* __restrict__ x,
    const float* __restrict__ A,
    const float* __restrict__ B,
    const int* __restrict__ deg,
    const float* __restrict__ W_rxnode,
    const float* __restrict__ P,
    float* __restrict__ out0,
    float* __restrict__ out1,
    int N_) {
    const int n = blockIdx.x * 256 + threadIdx.x;
    if (n >= N_) return;

    float xr[D];
    #pragma unroll
    for (int kq = 0; kq < D / 4; ++kq)
        *(float4*)(xr + kq * 4) = *(const float4*)(x + (size_t)n * D + kq * 4);

    {
        float o[D];
        #pragma unroll
        for (int j = 0; j < D; ++j) {
            float s = 0.f;
            #pragma unroll
            for (int k = 0; k < D; ++k) s += xr[k] * W_rxnode[j * D + k];
            o[j] = s;
        }
        #pragma unroll
        for (int kq = 0; kq < D / 4; ++kq)
            *(float4*)(out0 + (size_t)n * D + kq * 4) = *(const float4*)(o + kq * 4);
    }

    float Ar[D], Br[D];
    #pragma unroll
    for (int kq = 0; kq < D / 4; ++kq) {
        *(float4*)(Ar + kq * 4) = *(const float4*)(A + (size_t)n * D + kq * 4);
        *(float4*)(Br + kq * 4) = *(const float4*)(B + (size_t)n * D + kq * 4);
    }
    const float dg = (float)deg[n];
    #pragma unroll
    for (int k = 0; k < D; ++k) xr[k] *= dg;  // fold deg into x row

    const float* __restrict__ Ps = P;
    const float* __restrict__ Pe = P + D * D;
    const float* __restrict__ Pr = P + 2 * D * D;
    {
        float o[D];
        #pragma unroll
        for (int j = 0; j < D; ++j) {
            float s = 0.f;
            #pragma unroll
            for (int k = 0; k < D; ++k) {
                s += Ar[k] * Ps[j * D + k];
                s += Br[k] * Pe[j * D + k];
                s += xr[k] * Pr[j * D + k];
            }
            o[j] = s;
        }
        #pragma unroll
        for (int kq = 0; kq < D / 4; ++kq)
            *(float4*)(out1 + (size_t)n * D + kq * 4) = *(const float4*)(o + kq * 4);
    }
}

extern "C" void kernel_launch(void* const* d_in, const int* in_sizes, int n_in,
                              void* d_out, int out_size, void* d_ws, size_t ws_size,
                              hipStream_t stream) {
    const float* x        = (const float*)d_in[0];
    const int*   ei       = (const int*)d_in[1];    // [2, E] int32
    const float* ea       = (const float*)d_in[2];  // [E, D]
    const float* W_src    = (const float*)d_in[3];
    const float* W_edge   = (const float*)d_in[4];
    const float* W_rx     = (const float*)d_in[5];
    const float* W_eu     = (const float*)d_in[6];
    const float* W_rxnode = (const float*)d_in[7];
    const float* W_aggr   = (const float*)d_in[8];

    const int N_ = in_sizes[0] / D;  // 100000
    const int E_ = in_sizes[2] / D;  // 2000000
    const int NBINS = (N_ + GN - 1) / GN;

    // ws layout: A[N*D] | B[N*D] | cntfb[N] | cursor[NBINS] | ovf[1]  (zeroed)
    //            | deg[N] | P[3*D*D] | pad | binbuf[NBINS*CAPB] uint2
    float* A      = (float*)d_ws;
    float* B      = A + (size_t)N_ * D;
    int*   cntfb  = (int*)(B + (size_t)N_ * D);
    int*   cursor = cntfb + N_;
    int*   ovf    = cursor + NBINS;
    int*   deg    = ovf + 1;
    float* P      = (float*)(deg + N_);
    size_t off = ((size_t)2 * N_ * D + 2 * N_ + NBINS + 1 + 3 * D * D) * 4;
    off = (off + 15) & ~(size_t)15;
    uint2* binbuf = (uint2*)((char*)d_ws + off);

    int CAPB = 0;
    if (ws_size > off) {
        size_t c = (ws_size - off) / ((size_t)NBINS * 8);
        CAPB = (c > CAPB_MAX) ? CAPB_MAX : (int)c;
    }

    float* out0 = (float*)d_out;
    float* out1 = out0 + (size_t)N_ * D;

    // zero A, B, cntfb, cursor, ovf (contiguous)
    hipMemsetAsync(d_ws, 0, ((size_t)2 * N_ * D + N_ + NBINS + 1) * sizeof(float), stream);

    combine_weights<<<1, dim3(32, 32), 0, stream>>>(W_src, W_edge, W_rx, W_eu, W_aggr, P);

    const int gridA = (E_ + CHUNK_A - 1) / CHUNK_A;
    const size_t smA = (size_t)(2 * NBINS + CHUNK_A) * sizeof(int);
    bucket<<<gridA, THREADS_A, smA, stream>>>(
        ei, x, ea, cursor, binbuf, A, B, cntfb, ovf, E_, NBINS, CAPB);

    bin_gather<<<NBINS, THREADS_G, 0, stream>>>(
        x, ea, binbuf, cursor, A, B, cntfb, ovf, A, B, deg, N_, CAPB);

    node_kernel<<<(N_ + 255) / 256, 256, 0, stream>>>(
        x, A, B, deg, W_rxnode, P, out0, out1, N_);
}